// Round 1
// baseline (130.638 us; speedup 1.0000x reference)
//
#include <hip/hip_runtime.h>
#include <hip/hip_cooperative_groups.h>
#include <math.h>

namespace cg = cooperative_groups;

#define BB 8
#define HH 256
#define WW 256
#define NPIX (BB*HH*WW)   // 524288
#define BIGF 512.0f       // H + W, the reference cap
#define INF9 1e9f

// ws layout (floats): gA2 [0,524288) | gB2 [524288,1048576) |
//                     partials: 16 slots, stride 32 floats (128 B) | counter (int)
#define P_OFF   (2 * NPIX)
#define P_STRIDE 32
#define C_OFF   (P_OFF + 16 * P_STRIDE)

// ---------------------------------------------------------------------------
// Wave-parallel vertical min-plus scan for ONE feature set.
// Lane l owns rows 4l..4l+3; Hillis-Steele min-plus doubling over 64 lanes.
// ---------------------------------------------------------------------------
__device__ __forceinline__ void col_scan_g2(bool f0, bool f1, bool f2, bool f3,
                                            int lane, float g2[4]) {
  float d = INF9;
  d = f0 ? 0.0f : d + 1.0f; float lf0 = d;
  d = f1 ? 0.0f : d + 1.0f; float lf1 = d;
  d = f2 ? 0.0f : d + 1.0f; float lf2 = d;
  d = f3 ? 0.0f : d + 1.0f; float lf3 = d;
  float F = lf3;
#pragma unroll
  for (int s = 1; s < 64; s <<= 1) {
    float u = __shfl_up(F, s, 64) + 4.0f * (float)s;
    if (lane >= s) F = fminf(F, u);
  }
  float Fe = __shfl_up(F, 1, 64);
  if (lane == 0) Fe = INF9;

  d = INF9;
  d = f3 ? 0.0f : d + 1.0f; float lb3 = d;
  d = f2 ? 0.0f : d + 1.0f; float lb2 = d;
  d = f1 ? 0.0f : d + 1.0f; float lb1 = d;
  d = f0 ? 0.0f : d + 1.0f; float lb0 = d;
  float Bv = lb0;
#pragma unroll
  for (int s = 1; s < 64; s <<= 1) {
    float u = __shfl_down(Bv, s, 64) + 4.0f * (float)s;
    if (lane < 64 - s) Bv = fminf(Bv, u);
  }
  float Be = __shfl_down(Bv, 1, 64);
  if (lane == 63) Be = INF9;

  float v0 = fminf(fminf(lf0, Fe + 1.0f), fminf(lb0, Be + 4.0f));
  float v1 = fminf(fminf(lf1, Fe + 2.0f), fminf(lb1, Be + 3.0f));
  float v2 = fminf(fminf(lf2, Fe + 3.0f), fminf(lb2, Be + 2.0f));
  float v3 = fminf(fminf(lf3, Fe + 4.0f), fminf(lb3, Be + 1.0f));
  v0 = fminf(v0, BIGF); v1 = fminf(v1, BIGF);
  v2 = fminf(v2, BIGF); v3 = fminf(v3, BIGF);
  g2[0] = v0 * v0; g2[1] = v1 * v1; g2[2] = v2 * v2; g2[3] = v3 * v3;
}

#define ENV_GROUP(kk) { float4 v = s4[kk];                        \
    float D0 = fw - (float)(4 * (kk));                            \
    d2 = fminf(d2, fmaf(D0, D0, v.x));                            \
    float D1 = D0 - 1.0f; d2 = fminf(d2, fmaf(D1, D1, v.y));      \
    float D2 = D0 - 2.0f; d2 = fminf(d2, fmaf(D2, D2, v.z));      \
    float D3 = D0 - 3.0f; d2 = fminf(d2, fmaf(D3, D3, v.w)); }

// ---------------------------------------------------------------------------
// Fused cooperative kernel: 256 blocks x 1024 threads (1 block/CU co-resident).
// Phase 1: vertical EDT — 8 columns x 2 features = 16 waves/block, one
//          (column,feature) per wave (halves the shuffle-chain critical path
//          vs. one wave doing both features).
// grid.sync()
// Phase 2: row-envelope + loss for two 4-row groups per block, with all
//          global loads software-pipelined ahead of the compute.
// ---------------------------------------------------------------------------
__global__ __launch_bounds__(1024) void fused_boundary_loss(
    const float* __restrict__ pred,
    const float* __restrict__ tgt,
    float* __restrict__ ws,
    float* __restrict__ out) {
  __shared__ __align__(16) float lA[4][WW];
  __shared__ __align__(16) float lB[4][WW];
  __shared__ float wsum[16];
  __shared__ int lastFlag;

  float* gA2 = ws;
  float* gB2 = ws + NPIX;
  float* partials = ws + P_OFF;
  int* counter = ((int*)ws) + C_OFF;

  int tid = threadIdx.x;

  // zero reduction state for this launch (visible to all after grid.sync)
  if (blockIdx.x == 0) {
    if (tid < 16) partials[tid * P_STRIDE] = 0.0f;
    if (tid == 16) *counter = 0;
  }

  // ---- prefetch phase-2 pred/tgt (independent of phase 1) ----
  float xx[2], tt[2];
#pragma unroll
  for (int it = 0; it < 2; ++it) {
    size_t base = (size_t)((int)blockIdx.x + (it << 8)) * (4 * WW);
    xx[it] = pred[base + tid];
    tt[it] = tgt[base + tid];
  }

  // ---- phase 1: vertical EDT, one (column, feature) per wave ----
  {
    int widx = tid >> 6;
    int lane = tid & 63;
    int col  = ((int)blockIdx.x << 3) | (widx & 7);  // 256*8 = 2048 columns
    int feat = widx >> 3;                            // 0 => A (bg), 1 => B (fg)
    int b = col >> 8;
    int w = col & 255;
    size_t ibase = (size_t)b * (HH * WW) + w;

    float t0 = tgt[ibase + (size_t)(4 * lane + 0) * WW];
    float t1 = tgt[ibase + (size_t)(4 * lane + 1) * WW];
    float t2 = tgt[ibase + (size_t)(4 * lane + 2) * WW];
    float t3 = tgt[ibase + (size_t)(4 * lane + 3) * WW];
    bool p0 = t0 > 0.5f, p1 = t1 > 0.5f, p2 = t2 > 0.5f, p3 = t3 > 0.5f;
    bool f0 = feat ? p0 : !p0;
    bool f1 = feat ? p1 : !p1;
    bool f2 = feat ? p2 : !p2;
    bool f3 = feat ? p3 : !p3;

    float g2v[4];
    col_scan_g2(f0, f1, f2, f3, lane, g2v);

    float* dst = feat ? gB2 : gA2;
#pragma unroll
    for (int k = 0; k < 4; ++k)
      dst[ibase + (size_t)(4 * lane + k) * WW] = g2v[k];
  }

  cg::this_grid().sync();

  // ---- phase 2: row envelope + loss, two row-groups per block ----
  int r = tid >> 8;    // row within 4-row group
  int w = tid & 255;   // column
  int w0 = w & ~63;    // wave-uniform block base
  int kc0 = w0 >> 2;   // first own j-group
  float fw = (float)w;

  // prefetch both row-groups' g2 rows (valid after grid.sync)
  float la[2], lb[2];
#pragma unroll
  for (int it = 0; it < 2; ++it) {
    size_t base = (size_t)((int)blockIdx.x + (it << 8)) * (4 * WW);
    la[it] = gA2[base + tid];
    lb[it] = gB2[base + tid];
  }

  float acc = 0.0f;
#pragma unroll
  for (int it = 0; it < 2; ++it) {
    __syncthreads();
    ((float*)lA)[tid] = la[it];
    ((float*)lB)[tid] = lb[it];
    __syncthreads();

    float x = xx[it];
    float t = tt[it];
    bool fg = t > 0.5f;
    const float4* s4 = (const float4*)(fg ? lA[r] : lB[r]);

    float d2 = 1e30f;
    // own 64-column block: 16 groups (covers |w-j| up to 63 one-sided)
#pragma unroll 4
    for (int k = kc0; k < kc0 + 16; ++k) ENV_GROUP(k);

    // center-out rings with wave-uniform exact early exit
    int kL = kc0 - 1;
    int kR = kc0 + 16;
    for (int iter = 0; iter < 16; ++iter) {
      int bL = (kL >= 0) ? (w0 - 4 * kL - 3) : 100000;
      int bR = (kR <= 63) ? (4 * kR - w0 - 63) : 100000;
      int bb = min(bL, bR);
      float bb2 = (float)bb * (float)bb;
      if (__all(d2 <= bb2)) break;
      if (kL >= 0) { ENV_GROUP(kL); kL--; }
      if (kR <= 63) { ENV_GROUP(kR); kR++; }
    }

    float dd = sqrtf(d2);
    float weight = 1.0f / (1.0f + __expf((dd - 3.0f) * 0.2f));
    float bce = fmaxf(x, 0.0f) - x * t + log1pf(__expf(-fabsf(x)));
    acc += bce * weight;
  }

  float c = acc * (1.0f / (float)NPIX);

#pragma unroll
  for (int off = 32; off > 0; off >>= 1) c += __shfl_down(c, off, 64);
  if ((tid & 63) == 0) wsum[tid >> 6] = c;
  __syncthreads();

  if (tid < 64) {
    float v = (tid < 16) ? wsum[tid] : 0.0f;
#pragma unroll
    for (int off = 8; off > 0; off >>= 1) v += __shfl_down(v, off, 64);
    if (tid == 0) {
      atomicAdd(&partials[(blockIdx.x & 15) * P_STRIDE], v);
      __threadfence();
      int done = atomicAdd(counter, 1);
      lastFlag = (done == (int)gridDim.x - 1) ? 1 : 0;
    }
  }
  __syncthreads();

  if (lastFlag && tid < 64) {
    float v = (tid < 16) ? atomicAdd(&partials[tid * P_STRIDE], 0.0f) : 0.0f;
#pragma unroll
    for (int off = 8; off > 0; off >>= 1) v += __shfl_down(v, off, 64);
    if (tid == 0) out[0] = v;
  }
}

extern "C" void kernel_launch(void* const* d_in, const int* in_sizes, int n_in,
                              void* d_out, int out_size, void* d_ws, size_t ws_size,
                              hipStream_t stream) {
  const float* pred = (const float*)d_in[0];
  const float* tgt  = (const float*)d_in[1];
  float* out = (float*)d_out;
  float* ws  = (float*)d_ws;

  void* args[] = {(void*)&pred, (void*)&tgt, (void*)&ws, (void*)&out};
  hipLaunchCooperativeKernel((const void*)fused_boundary_loss,
                             dim3(256), dim3(1024), args, 0, stream);
}

// Round 2
// 75.880 us; speedup vs baseline: 1.7216x; 1.7216x over previous
//
#include <hip/hip_runtime.h>
#include <math.h>

#define BB 8
#define HH 256
#define WW 256
#define NPIX (BB*HH*WW)   // 524288
#define BIGI 512          // H + W, the reference cap
#define BIGBIG (1<<20)

// ws layout (floats): gA2 [0,524288) | gB2 [524288,1048576) |
//                     partials: 16 slots, stride 32 floats (128 B) | counter (int)
#define P_OFF   (2 * NPIX)
#define P_STRIDE 32
#define C_OFF   (P_OFF + 16 * P_STRIDE)

// ---------------------------------------------------------------------------
// Kernel 1 (rewritten): vertical EDT via bit-packed columns.
// Grid 32 blocks x 512 threads. Block = 64 columns of one image.
// Wave k (k=0..7) packs rows [32k,32k+32) : lane = column, rows read
// COALESCED (256B per load across the wave), 1 bit per pixel -> u32 word.
// Masks shared via 2KB LDS. Then each wave computes exact distances for its
// 32 rows fully in-lane with clz/ctz (no shuffles, no scattered loads):
//   fwd dist at row rr:  x = m << (31-rr);  d = x ? clz(x) : rr+1+carry_below
//   bwd dist at row rr:  y = m >> rr;       d = y ? ctz(y) : 32-rr+carry_above
// Carries across the 8 words are tiny select-chains. Both feature sets
// (A = background = ~fg, B = fg) from the same masks. Cap at 512, square.
// Also zeroes the reduction partials + counter for kernel 2.
// ---------------------------------------------------------------------------
__global__ __launch_bounds__(512) void edt_vertical_bits(
    const float* __restrict__ tgt,
    float* __restrict__ ws) {
  __shared__ unsigned int smem[8 * 64];

  if (blockIdx.x == 0) {
    if (threadIdx.x < 16) ws[P_OFF + threadIdx.x * P_STRIDE] = 0.0f;
    if (threadIdx.x == 16) ((int*)ws)[C_OFF] = 0;
  }

  float* gA2 = ws;
  float* gB2 = ws + NPIX;

  int k = threadIdx.x >> 6;   // wave id = word id (rows 32k..32k+31)
  int l = threadIdx.x & 63;   // column within 64-col tile
  int b = blockIdx.x >> 2;    // image
  int w0 = (blockIdx.x & 3) << 6;
  size_t ibase = (size_t)b * (HH * WW) + (size_t)w0 + l;

  // ---- pack 32 rows (coalesced loads) ----
  unsigned int m = 0;
#pragma unroll
  for (int i = 0; i < 32; ++i) {
    float t = tgt[ibase + (size_t)(32 * k + i) * WW];
    m |= (t > 0.5f ? 1u : 0u) << i;
  }
  smem[k * 64 + l] = m;
  __syncthreads();

  unsigned int Mf[8];
#pragma unroll
  for (int j = 0; j < 8; ++j) Mf[j] = smem[j * 64 + l];

  // ---- cross-word carries (A = ~fg, B = fg) ----
  int fcA = BIGBIG, fcB = BIGBIG;
  {
    int cA = BIGBIG, cB = BIGBIG;
#pragma unroll
    for (int j = 0; j < 8; ++j) {
      if (j == k) { fcA = cA; fcB = cB; }
      unsigned int a = ~Mf[j], bm = Mf[j];
      cA = a  ? (int)__builtin_clz(a)  : cA + 32;
      cB = bm ? (int)__builtin_clz(bm) : cB + 32;
    }
  }
  int bcA = BIGBIG, bcB = BIGBIG;
  {
    int cA = BIGBIG, cB = BIGBIG;
#pragma unroll
    for (int j = 7; j >= 0; --j) {
      if (j == k) { bcA = cA; bcB = cB; }
      unsigned int a = ~Mf[j], bm = Mf[j];
      cA = a  ? (int)__builtin_ctz(a)  : cA + 32;
      cB = bm ? (int)__builtin_ctz(bm) : cB + 32;
    }
  }

  // ---- per-row exact distances, both features, all in-lane ----
  unsigned int mB = m;     // own word (fg)
  unsigned int mA = ~m;    // own word (bg)
  size_t obase = ibase + (size_t)(32 * k) * WW;

#pragma unroll 8
  for (int rr = 0; rr < 32; ++rr) {
    // A: feature = background
    {
      unsigned int x = mA << (31 - rr);
      unsigned int y = mA >> rr;
      int df = x ? (int)__builtin_clz(x) : (rr + 1 + fcA);
      int db = y ? (int)__builtin_ctz(y) : (32 - rr + bcA);
      int d = min(min(df, db), BIGI);
      gA2[obase + (size_t)rr * WW] = (float)(d * d);
    }
    // B: feature = fg
    {
      unsigned int x = mB << (31 - rr);
      unsigned int y = mB >> rr;
      int df = x ? (int)__builtin_clz(x) : (rr + 1 + fcB);
      int db = y ? (int)__builtin_ctz(y) : (32 - rr + bcB);
      int d = min(min(df, db), BIGI);
      gB2[obase + (size_t)rr * WW] = (float)(d * d);
    }
  }
}

// ---------------------------------------------------------------------------
// Kernel 2: UNCHANGED from the 80.8us baseline. 4 rows per block (1024
// threads, 16 waves). Center-out lower envelope with wave-uniform early exit,
// capped at the +-64 window (weight < 5e-6 beyond). Wave shuffle -> LDS ->
// one spread atomicAdd per block; last block sums 16 partials.
// ---------------------------------------------------------------------------
#define ENV_GROUP(kk) { float4 v = s4[kk];                        \
    float D0 = fw - (float)(4 * (kk));                            \
    d2 = fminf(d2, fmaf(D0, D0, v.x));                            \
    float D1 = D0 - 1.0f; d2 = fminf(d2, fmaf(D1, D1, v.y));      \
    float D2 = D0 - 2.0f; d2 = fminf(d2, fmaf(D2, D2, v.z));      \
    float D3 = D0 - 3.0f; d2 = fminf(d2, fmaf(D3, D3, v.w)); }

__global__ __launch_bounds__(1024) void edt_row_loss3(
    const float* __restrict__ pred,
    const float* __restrict__ tgt,
    float* __restrict__ ws,
    float* __restrict__ out) {
  __shared__ __align__(16) float lA[4][WW];
  __shared__ __align__(16) float lB[4][WW];
  __shared__ float wsum[16];
  __shared__ int lastFlag;

  const float* gA2 = ws;
  const float* gB2 = ws + NPIX;
  float* partials = ws + P_OFF;
  int* counter = ((int*)ws) + C_OFF;

  int tid = threadIdx.x;
  size_t base = (size_t)blockIdx.x * (4 * WW);

  ((float*)lA)[tid] = gA2[base + tid];
  ((float*)lB)[tid] = gB2[base + tid];
  float x = pred[base + tid];
  float t = tgt[base + tid];
  __syncthreads();

  int r = tid >> 8;    // row within block
  int w = tid & 255;   // column
  bool fg = t > 0.5f;
  const float4* s4 = (const float4*)(fg ? lA[r] : lB[r]);

  int w0 = w & ~63;          // wave-uniform block base
  int kc0 = w0 >> 2;         // first own j-group
  float fw = (float)w;
  float d2 = 1e30f;

  // own 64-column block: 16 groups (covers |w-j| up to 63 one-sided)
#pragma unroll 4
  for (int k = kc0; k < kc0 + 16; ++k) ENV_GROUP(k);

  // center-out rings with wave-uniform exact early exit
  int kL = kc0 - 1;
  int kR = kc0 + 16;
  for (int iter = 0; iter < 16; ++iter) {
    int bL = (kL >= 0) ? (w0 - 4 * kL - 3) : 100000;   // nearest unscanned left
    int bR = (kR <= 63) ? (4 * kR - w0 - 63) : 100000; // nearest unscanned right
    int bb = min(bL, bR);
    float bb2 = (float)bb * (float)bb;
    if (__all(d2 <= bb2)) break;
    if (kL >= 0) { ENV_GROUP(kL); kL--; }
    if (kR <= 63) { ENV_GROUP(kR); kR++; }
  }

  float dd = sqrtf(d2);
  float weight = 1.0f / (1.0f + __expf((dd - 3.0f) * 0.2f));
  float bce = fmaxf(x, 0.0f) - x * t + log1pf(__expf(-fabsf(x)));
  float c = bce * weight * (1.0f / (float)NPIX);

#pragma unroll
  for (int off = 32; off > 0; off >>= 1) c += __shfl_down(c, off, 64);
  if ((tid & 63) == 0) wsum[tid >> 6] = c;
  __syncthreads();

  if (tid < 64) {
    float v = (tid < 16) ? wsum[tid] : 0.0f;
#pragma unroll
    for (int off = 8; off > 0; off >>= 1) v += __shfl_down(v, off, 64);
    if (tid == 0) {
      atomicAdd(&partials[(blockIdx.x & 15) * P_STRIDE], v);
      __threadfence();
      int done = atomicAdd(counter, 1);
      lastFlag = (done == (int)gridDim.x - 1) ? 1 : 0;
    }
  }
  __syncthreads();

  if (lastFlag && tid < 64) {
    float v = (tid < 16) ? atomicAdd(&partials[tid * P_STRIDE], 0.0f) : 0.0f;
#pragma unroll
    for (int off = 8; off > 0; off >>= 1) v += __shfl_down(v, off, 64);
    if (tid == 0) out[0] = v;
  }
}

extern "C" void kernel_launch(void* const* d_in, const int* in_sizes, int n_in,
                              void* d_out, int out_size, void* d_ws, size_t ws_size,
                              hipStream_t stream) {
  const float* pred = (const float*)d_in[0];
  const float* tgt  = (const float*)d_in[1];
  float* out = (float*)d_out;
  float* ws  = (float*)d_ws;

  edt_vertical_bits<<<dim3(32), dim3(512), 0, stream>>>(tgt, ws);
  edt_row_loss3<<<dim3(512), dim3(1024), 0, stream>>>(pred, tgt, ws, out);
}

// Round 3
// 71.078 us; speedup vs baseline: 1.8379x; 1.0676x over previous
//
#include <hip/hip_runtime.h>
#include <math.h>

#define BB 8
#define HH 256
#define WW 256
#define NPIX (BB*HH*WW)   // 524288
#define BIGI 512          // H + W, the reference cap
#define BIGBIG (1<<20)

// ws layout: masks (u32) [0, 16384) = 64 KB : mask[im][j][w], im=0..7 image,
//            j=0..7 word (rows 32j..32j+31), w=0..255 column.
//            partials: 16 slots, stride 32 floats (128 B) | counter (int)
//            (P_OFF kept beyond the old 2*NPIX region; ws is large)
#define P_OFF   (2 * NPIX)
#define P_STRIDE 32
#define C_OFF   (P_OFF + 16 * P_STRIDE)

// ---------------------------------------------------------------------------
// Kernel 1: pack target into per-column bitmasks. Grid 64 x 256.
// Block = 32 columns of one image; thread (j = tid>>5, c = tid&31) packs
// word j (rows 32j..32j+31) of column w0+c with 32 coalesced row-reads.
// Writes 64 KB total. Also zeroes the reduction partials + counter.
// ---------------------------------------------------------------------------
__global__ __launch_bounds__(256) void pack_masks(
    const float* __restrict__ tgt,
    float* __restrict__ ws) {
  if (blockIdx.x == 0) {
    if (threadIdx.x < 16) ws[P_OFF + threadIdx.x * P_STRIDE] = 0.0f;
    if (threadIdx.x == 16) ((int*)ws)[C_OFF] = 0;
  }

  unsigned int* maskws = (unsigned int*)ws;
  int j = threadIdx.x >> 5;                 // word id 0..7
  int c = threadIdx.x & 31;                 // col within tile
  int im = blockIdx.x >> 3;                 // image
  int w = ((blockIdx.x & 7) << 5) + c;      // column 0..255
  size_t ibase = (size_t)im * (HH * WW) + w;

  unsigned int m = 0;
#pragma unroll
  for (int i = 0; i < 32; ++i) {
    float t = tgt[ibase + (size_t)(32 * j + i) * WW];
    m |= (t > 0.5f ? 1u : 0u) << i;
  }
  maskws[im * 2048 + j * 256 + w] = m;
}

// ---------------------------------------------------------------------------
// Kernel 2: per-pixel vertical distance from bitmasks (clz/ctz + carry
// chains — identical arithmetic to the verified round-2 kernel), then the
// unchanged center-out lower envelope + loss + two-level reduction.
// Reads: masks (8 x u32 per thread, L2-hot) + pred (coalesced). No tgt read:
// t is reconstructed exactly from the mask bit (targets are binary 0/1).
// ---------------------------------------------------------------------------
#define ENV_GROUP(kk) { float4 v = s4[kk];                        \
    float D0 = fw - (float)(4 * (kk));                            \
    d2 = fminf(d2, fmaf(D0, D0, v.x));                            \
    float D1 = D0 - 1.0f; d2 = fminf(d2, fmaf(D1, D1, v.y));      \
    float D2 = D0 - 2.0f; d2 = fminf(d2, fmaf(D2, D2, v.z));      \
    float D3 = D0 - 3.0f; d2 = fminf(d2, fmaf(D3, D3, v.w)); }

__global__ __launch_bounds__(1024) void edt_row_loss4(
    const float* __restrict__ pred,
    float* __restrict__ ws,
    float* __restrict__ out) {
  __shared__ __align__(16) float lA[4][WW];
  __shared__ __align__(16) float lB[4][WW];
  __shared__ float wsum[16];
  __shared__ int lastFlag;

  const unsigned int* maskws = (const unsigned int*)ws;
  float* partials = ws + P_OFF;
  int* counter = ((int*)ws) + C_OFF;

  int tid = threadIdx.x;
  int im = blockIdx.x >> 6;   // image
  int rg = blockIdx.x & 63;   // row-group (4 rows)
  int r = tid >> 8;           // row within group (wave-uniform)
  int w = tid & 255;          // column
  int R = 4 * rg + r;         // row in image
  int k = R >> 5;             // word id (wave-uniform: 4rg..4rg+3 same word)
  int rr = R & 31;            // bit within word

  // 8 mask words of column w (coalesced across lanes; L2-hot)
  unsigned int M[8];
#pragma unroll
  for (int j = 0; j < 8; ++j) M[j] = maskws[im * 2048 + j * 256 + w];

  float x = pred[(size_t)blockIdx.x * (4 * WW) + tid];

  // cross-word carries (A = bg = ~fg, B = fg) — verified select chains
  int fcA = BIGBIG, fcB = BIGBIG, bcA = BIGBIG, bcB = BIGBIG;
  {
    int cA = BIGBIG, cB = BIGBIG;
#pragma unroll
    for (int j = 0; j < 8; ++j) {
      if (j == k) { fcA = cA; fcB = cB; }
      unsigned int a = ~M[j], bm = M[j];
      cA = a  ? (int)__builtin_clz(a)  : cA + 32;
      cB = bm ? (int)__builtin_clz(bm) : cB + 32;
    }
  }
  {
    int cA = BIGBIG, cB = BIGBIG;
#pragma unroll
    for (int j = 7; j >= 0; --j) {
      if (j == k) { bcA = cA; bcB = cB; }
      unsigned int a = ~M[j], bm = M[j];
      cA = a  ? (int)__builtin_ctz(a)  : cA + 32;
      cB = bm ? (int)__builtin_ctz(bm) : cB + 32;
    }
  }

  unsigned int mk = M[k];
  bool fg = (mk >> rr) & 1u;
  float t = fg ? 1.0f : 0.0f;

  // vertical distances for this pixel, both feature sets
  {
    unsigned int mA = ~mk;
    unsigned int xx = mA << (31 - rr);
    unsigned int yy = mA >> rr;
    int df = xx ? (int)__builtin_clz(xx) : (rr + 1 + fcA);
    int db = yy ? (int)__builtin_ctz(yy) : (32 - rr + bcA);
    int d = min(min(df, db), BIGI);
    lA[r][w] = (float)(d * d);
  }
  {
    unsigned int mB = mk;
    unsigned int xx = mB << (31 - rr);
    unsigned int yy = mB >> rr;
    int df = xx ? (int)__builtin_clz(xx) : (rr + 1 + fcB);
    int db = yy ? (int)__builtin_ctz(yy) : (32 - rr + bcB);
    int d = min(min(df, db), BIGI);
    lB[r][w] = (float)(d * d);
  }
  __syncthreads();

  const float4* s4 = (const float4*)(fg ? lA[r] : lB[r]);

  int w0 = w & ~63;          // wave-uniform block base
  int kc0 = w0 >> 2;         // first own j-group
  float fw = (float)w;
  float d2 = 1e30f;

  // own 64-column block: 16 groups (covers |w-j| up to 63 one-sided)
#pragma unroll 4
  for (int kk = kc0; kk < kc0 + 16; ++kk) ENV_GROUP(kk);

  // center-out rings with wave-uniform exact early exit
  int kL = kc0 - 1;
  int kR = kc0 + 16;
  for (int iter = 0; iter < 16; ++iter) {
    int bL = (kL >= 0) ? (w0 - 4 * kL - 3) : 100000;   // nearest unscanned left
    int bR = (kR <= 63) ? (4 * kR - w0 - 63) : 100000; // nearest unscanned right
    int bb = min(bL, bR);
    float bb2 = (float)bb * (float)bb;
    if (__all(d2 <= bb2)) break;
    if (kL >= 0) { ENV_GROUP(kL); kL--; }
    if (kR <= 63) { ENV_GROUP(kR); kR++; }
  }

  float dd = sqrtf(d2);
  float weight = 1.0f / (1.0f + __expf((dd - 3.0f) * 0.2f));
  float bce = fmaxf(x, 0.0f) - x * t + log1pf(__expf(-fabsf(x)));
  float c = bce * weight * (1.0f / (float)NPIX);

#pragma unroll
  for (int off = 32; off > 0; off >>= 1) c += __shfl_down(c, off, 64);
  if ((tid & 63) == 0) wsum[tid >> 6] = c;
  __syncthreads();

  if (tid < 64) {
    float v = (tid < 16) ? wsum[tid] : 0.0f;
#pragma unroll
    for (int off = 8; off > 0; off >>= 1) v += __shfl_down(v, off, 64);
    if (tid == 0) {
      atomicAdd(&partials[(blockIdx.x & 15) * P_STRIDE], v);
      __threadfence();
      int done = atomicAdd(counter, 1);
      lastFlag = (done == (int)gridDim.x - 1) ? 1 : 0;
    }
  }
  __syncthreads();

  if (lastFlag && tid < 64) {
    float v = (tid < 16) ? atomicAdd(&partials[tid * P_STRIDE], 0.0f) : 0.0f;
#pragma unroll
    for (int off = 8; off > 0; off >>= 1) v += __shfl_down(v, off, 64);
    if (tid == 0) out[0] = v;
  }
}

extern "C" void kernel_launch(void* const* d_in, const int* in_sizes, int n_in,
                              void* d_out, int out_size, void* d_ws, size_t ws_size,
                              hipStream_t stream) {
  const float* pred = (const float*)d_in[0];
  const float* tgt  = (const float*)d_in[1];
  float* out = (float*)d_out;
  float* ws  = (float*)d_ws;

  pack_masks<<<dim3(64), dim3(256), 0, stream>>>(tgt, ws);
  edt_row_loss4<<<dim3(512), dim3(1024), 0, stream>>>(pred, ws, out);
}